// Round 1
// 693.856 us; speedup vs baseline: 1.0699x; 1.0699x over previous
//
#include <hip/hip_runtime.h>
#include <cstdint>

// ---- problem constants ----
constexpr int Bn = 8, Tn = 64, En = 128, Cn = 256;
constexpr int Hn = 512, Mn = 1024, NHd = 8, Dn = 32;
constexpr int NTOK = Bn * Tn * En;          // 65536 tokens
constexpr size_t SZ = (size_t)NTOK * Cn;    // 16,777,216 elements
#define EPSF 1e-5f

typedef __attribute__((ext_vector_type(8))) short short8;
typedef __attribute__((ext_vector_type(4))) float f32x4;

__device__ __forceinline__ float bf2f(unsigned short u) {
  union { unsigned int i; float f; } c; c.i = ((unsigned int)u) << 16; return c.f;
}
__device__ __forceinline__ unsigned short f2bf(float f) {
  union { float f; unsigned int i; } c; c.f = f;
  unsigned int u = c.i;
  return (unsigned short)((u + 0x7fffu + ((u >> 16) & 1u)) >> 16);
}
__device__ __forceinline__ float gelu_f(float v) {
  return 0.5f * v * (1.0f + erff(v * 0.70710678118654752440f));
}

// async global->LDS, 16B per lane; lds dest = wave-uniform base + lane*16
__device__ __forceinline__ void gload16(const unsigned short* g, unsigned short* l) {
  __builtin_amdgcn_global_load_lds(
      (const __attribute__((address_space(1))) unsigned int*)g,
      (__attribute__((address_space(3))) unsigned int*)l, 16, 0, 0);
}

#define MEMFENCE() asm volatile("" ::: "memory")

// ---------------- MFMA GEMM: out[M,N] = A[M,K](bf16) @ Bt[N,K]^T (bf16) ------------
// 128x128 tile, BK=32, 256 threads (4 waves, each 64x64 via 4x4 16x16 frags).
// v2: explicit LDS double-buffer, raw s_barrier + counted vmcnt(4) so next tile's
//     global_load_lds stay in flight across the barrier (latency hidden under
//     compute of current tile), + XCD-chunked block swizzle for L2 A-panel reuse.
// EPI: 0 = bf16 plain; 1 = bf16 +bias; 2 = bf16 gelu(acc*scale+bias);
//      3 = f32 2*res + g*(acc*scale+bias); 4 = f32 res + acc + bias;
//      5 = f32 acc + bias.
// C1A: conv1 A-addressing over t-padded buffer [b][66][e][c], slab = k0>>8.
template <int EPI, bool C1A>
__global__ __launch_bounds__(256) void mfma_gemm(
    const unsigned short* __restrict__ A,
    const unsigned short* __restrict__ Bt,
    const float* __restrict__ scale,
    const float* __restrict__ bias,
    const float* __restrict__ resf,
    const float* __restrict__ gscal,
    void* __restrict__ outv,
    int K, int N) {
  __shared__ unsigned short As[2][128 * 32];
  __shared__ unsigned short Bs[2][128 * 32];
  int tid = threadIdx.x;
  int lane = tid & 63, wave = tid >> 6;

  // XCD-aware chunked swizzle (every grid here has nwg % 8 == 0).
  // Original flat id f runs on XCD f%8; remap so XCD x computes a contiguous
  // tile chunk -> consecutive ntiles of one mtile share an XCD's L2.
  int nwg = gridDim.x * gridDim.y;
  int flat = blockIdx.y * gridDim.x + blockIdx.x;
  int cpx = nwg >> 3;
  int swz = (flat & 7) * cpx + (flat >> 3);
  int ntile = swz % gridDim.x;
  int mtile = swz / gridDim.x;

  int rowBase = mtile * 128;
  int colBase = ntile * 128;
  int lda = C1A ? 256 : K;
  int r0 = lane >> 2;            // 0..15 row within 16-row chunk
  int c0 = (lane & 3) * 8;       // k-chunk (elements)
  f32x4 acc[4][4];
#pragma unroll
  for (int i = 0; i < 4; ++i)
#pragma unroll
    for (int j = 0; j < 4; ++j) acc[i][j] = (f32x4)(0.0f);
  int mbase = (wave >> 1) * 64;
  int nbase = (wave & 1) * 64;
  int arow = lane & 15;
  int akk = (lane >> 4) * 8;

  // issue 4 global_load_lds (per thread) for k-step k0 into buffer p
  auto stage = [&](int p, int k0) {
    size_t arowb; int kin;
    if (C1A) {
      int bb = mtile >> 6, tt = mtile & 63;
      int slab = k0 >> 8;                       // 0,1,2  <-> dt = slab-1
      arowb = (size_t)((bb * 66 + tt + slab) * 128);
      kin = k0 & 255;
    } else {
      arowb = (size_t)rowBase;
      kin = k0;
    }
#pragma unroll
    for (int i = 0; i < 2; ++i) {
      int q = i * 4 + wave;                     // 16-row chunk id, 0..7
      gload16(A + (arowb + q * 16 + r0) * (size_t)lda + kin + c0, &As[p][q * 512]);
      gload16(Bt + ((size_t)colBase + q * 16 + r0) * (size_t)K + k0 + c0, &Bs[p][q * 512]);
    }
  };
  auto compute = [&](int p) {
    short8 af[4], bfr[4];
#pragma unroll
    for (int i = 0; i < 4; ++i)
      af[i] = *(const short8*)&As[p][(mbase + i * 16 + arow) * 32 + akk];
#pragma unroll
    for (int j = 0; j < 4; ++j)
      bfr[j] = *(const short8*)&Bs[p][(nbase + j * 16 + arow) * 32 + akk];
#pragma unroll
    for (int i = 0; i < 4; ++i)
#pragma unroll
      for (int j = 0; j < 4; ++j)
        acc[i][j] = __builtin_amdgcn_mfma_f32_16x16x32_bf16(af[i], bfr[j], acc[i][j], 0, 0, 0);
  };

  stage(0, 0);                                  // 4 vm ops outstanding
  int nk = K >> 5;                              // in {8,16,24,32}: even, >= 8
  int t = 0;
  for (; t < nk - 2; t += 2) {
    // -- compute buf0 (k-step t), stage buf1 (k-step t+1) --
    MEMFENCE();
    __builtin_amdgcn_s_barrier();               // all waves done reading buf1
    MEMFENCE();
    stage(1, (t + 1) << 5);                     // outstanding: 8
    asm volatile("s_waitcnt vmcnt(4)" ::: "memory");  // my buf0 loads landed
    __builtin_amdgcn_sched_barrier(0);
    __builtin_amdgcn_s_barrier();               // everyone's buf0 landed
    MEMFENCE();
    __builtin_amdgcn_sched_barrier(0);
    compute(0);
    // -- compute buf1 (k-step t+1), stage buf0 (k-step t+2) --
    MEMFENCE();
    __builtin_amdgcn_s_barrier();               // all waves done reading buf0
    MEMFENCE();
    stage(0, (t + 2) << 5);                     // outstanding: 8
    asm volatile("s_waitcnt vmcnt(4)" ::: "memory");  // my buf1 loads landed
    __builtin_amdgcn_sched_barrier(0);
    __builtin_amdgcn_s_barrier();
    MEMFENCE();
    __builtin_amdgcn_sched_barrier(0);
    compute(1);
  }
  // tail: t == nk-2 (k-steps nk-2 and nk-1)
  MEMFENCE();
  __builtin_amdgcn_s_barrier();
  MEMFENCE();
  stage(1, (t + 1) << 5);
  asm volatile("s_waitcnt vmcnt(4)" ::: "memory");
  __builtin_amdgcn_sched_barrier(0);
  __builtin_amdgcn_s_barrier();
  MEMFENCE();
  __builtin_amdgcn_sched_barrier(0);
  compute(0);
  MEMFENCE();
  __builtin_amdgcn_s_barrier();
  asm volatile("s_waitcnt vmcnt(0)" ::: "memory");
  __builtin_amdgcn_sched_barrier(0);
  __builtin_amdgcn_s_barrier();
  MEMFENCE();
  __builtin_amdgcn_sched_barrier(0);
  compute(1);
  MEMFENCE();   // keep epilogue loads (bias/scale/resf) below the k-loop

  int crow0 = (lane >> 4) * 4;
  int ccol = lane & 15;
  float gt = (EPI == 3) ? gscal[0] : 0.f;
#pragma unroll
  for (int i = 0; i < 4; ++i) {
#pragma unroll
    for (int j = 0; j < 4; ++j) {
      int col = colBase + nbase + j * 16 + ccol;
      float sc = 1.f, bi = 0.f;
      if (EPI >= 1 && bias) bi = bias[col];
      if ((EPI == 2 || EPI == 3) && scale) sc = scale[col];
#pragma unroll
      for (int r = 0; r < 4; ++r) {
        size_t row = (size_t)rowBase + mbase + i * 16 + crow0 + r;
        size_t idx = row * (size_t)N + col;
        float v = acc[i][j][r];
        if (EPI == 0)      ((unsigned short*)outv)[idx] = f2bf(v);
        else if (EPI == 1) ((unsigned short*)outv)[idx] = f2bf(v + bi);
        else if (EPI == 2) ((unsigned short*)outv)[idx] = f2bf(gelu_f(v * sc + bi));
        else if (EPI == 3) ((float*)outv)[idx] = 2.0f * resf[idx] + gt * (v * sc + bi);
        else if (EPI == 4) ((float*)outv)[idx] = resf[idx] + v + bi;
        else if (EPI == 5) ((float*)outv)[idx] = v + bi;
      }
    }
  }
}

// ---------------- LayerNorm f32 -> bf16, one wave per token ------------------------
template <bool PAD>
__global__ __launch_bounds__(256) void ln256_bf(const float* __restrict__ src,
                                                const float* __restrict__ w,
                                                const float* __restrict__ b,
                                                unsigned short* __restrict__ dst) {
  int lane = threadIdx.x & 63;
  int tok = blockIdx.x * 4 + (threadIdx.x >> 6);
  const float4* row = (const float4*)(src + (size_t)tok * Cn);
  float4 v = row[lane];
  float s  = v.x + v.y + v.z + v.w;
  float s2 = v.x*v.x + v.y*v.y + v.z*v.z + v.w*v.w;
#pragma unroll
  for (int off = 32; off >= 1; off >>= 1) {
    s  += __shfl_xor(s, off, 64);
    s2 += __shfl_xor(s2, off, 64);
  }
  float mean = s * (1.0f / Cn);
  float var = fmaxf(s2 * (1.0f / Cn) - mean * mean, 0.0f);
  float r = rsqrtf(var + EPSF);
  float4 wv = ((const float4*)w)[lane];
  float4 bv = ((const float4*)b)[lane];
  size_t dtok = tok;
  if (PAD) {
    int bb = tok >> 13, tt = (tok >> 7) & 63, e = tok & 127;
    dtok = ((size_t)(bb * 66 + tt + 1)) * 128 + e;
  }
  ushort4 o;
  o.x = f2bf((v.x - mean) * r * wv.x + bv.x);
  o.y = f2bf((v.y - mean) * r * wv.y + bv.y);
  o.z = f2bf((v.z - mean) * r * wv.z + bv.z);
  o.w = f2bf((v.w - mean) * r * wv.w + bv.w);
  *(ushort4*)(dst + dtok * Cn + lane * 4) = o;
}

// ---------------- MFMA spatial attention, one block per (frame, head) --------------
// qkv: [bt*128+e][768]  (q|k|v each 256 wide, head h at h*32)
// maskh: 0.5 * adj  [128*128] f32.   P = maskh*S + 0.5  (== (S*m+1)*0.5)
__global__ __launch_bounds__(256) void attn_mfma(const unsigned short* __restrict__ qkv,
                                                 const float* __restrict__ maskh,
                                                 unsigned short* __restrict__ o) {
  __shared__ unsigned short Qs[128 * 32];
  __shared__ unsigned short Ks[128 * 32];
  __shared__ unsigned short Vt[32 * 136];    // [d][f], padded
  __shared__ unsigned short Ps[128 * 136];   // [e][f], padded
  int tid = threadIdx.x, lane = tid & 63, wave = tid >> 6;
  int h = blockIdx.x & 7, bt = blockIdx.x >> 3;
  size_t gbase = (size_t)bt * 128 * 768 + h * 32;
  // stage Q,K via global_load_lds (each wave: 2 chunks of 16 rows = 1 KB each)
#pragma unroll
  for (int i = 0; i < 2; ++i) {
    int q = wave * 2 + i;
    int row = q * 16 + (lane >> 2);
    int seg = (lane & 3) * 8;
    gload16(qkv + gbase + (size_t)row * 768 + seg, &Qs[q * 512]);
    gload16(qkv + gbase + 256 + (size_t)row * 768 + seg, &Ks[q * 512]);
  }
  // stage V transposed (scalar writes, ~2-way conflicts)
  {
    int e = tid >> 1, dh = (tid & 1) * 16;
    const unsigned short* gv = qkv + gbase + 512 + (size_t)e * 768 + dh;
    short8 v0 = *(const short8*)gv;
    short8 v1 = *(const short8*)(gv + 8);
#pragma unroll
    for (int j = 0; j < 8; ++j) {
      Vt[(dh + j) * 136 + e]     = (unsigned short)v0[j];
      Vt[(dh + 8 + j) * 136 + e] = (unsigned short)v1[j];
    }
  }
  __syncthreads();
  // ---- S = Q K^T for rows [32*wave, 32*wave+32), apply mask, write P to LDS ----
  int arow = lane & 15, akk = (lane >> 4) * 8;
  int crow0 = (lane >> 4) * 4, ccol = lane & 15;
  short8 af0 = *(const short8*)&Qs[(wave * 32 + arow) * 32 + akk];
  short8 af1 = *(const short8*)&Qs[(wave * 32 + 16 + arow) * 32 + akk];
#pragma unroll
  for (int j = 0; j < 8; ++j) {
    short8 bfr = *(const short8*)&Ks[(j * 16 + arow) * 32 + akk];
    f32x4 s0 = __builtin_amdgcn_mfma_f32_16x16x32_bf16(af0, bfr, (f32x4)(0.0f), 0, 0, 0);
    f32x4 s1 = __builtin_amdgcn_mfma_f32_16x16x32_bf16(af1, bfr, (f32x4)(0.0f), 0, 0, 0);
    int f = j * 16 + ccol;
#pragma unroll
    for (int r = 0; r < 4; ++r) {
      int e0 = wave * 32 + crow0 + r;
      int e1 = e0 + 16;
      Ps[e0 * 136 + f] = f2bf(maskh[e0 * 128 + f] * s0[r] + 0.5f);
      Ps[e1 * 136 + f] = f2bf(maskh[e1 * 128 + f] * s1[r] + 0.5f);
    }
  }
  // ---- O = P V for the same rows (wave reads only rows it wrote: no barrier) ----
  f32x4 acc[2][2];
#pragma unroll
  for (int i = 0; i < 2; ++i)
#pragma unroll
    for (int j = 0; j < 2; ++j) acc[i][j] = (f32x4)(0.0f);
#pragma unroll
  for (int k0 = 0; k0 < 128; k0 += 32) {
    short8 a0 = *(const short8*)&Ps[(wave * 32 + arow) * 136 + k0 + akk];
    short8 a1 = *(const short8*)&Ps[(wave * 32 + 16 + arow) * 136 + k0 + akk];
    short8 b0 = *(const short8*)&Vt[arow * 136 + k0 + akk];
    short8 b1 = *(const short8*)&Vt[(16 + arow) * 136 + k0 + akk];
    acc[0][0] = __builtin_amdgcn_mfma_f32_16x16x32_bf16(a0, b0, acc[0][0], 0, 0, 0);
    acc[0][1] = __builtin_amdgcn_mfma_f32_16x16x32_bf16(a0, b1, acc[0][1], 0, 0, 0);
    acc[1][0] = __builtin_amdgcn_mfma_f32_16x16x32_bf16(a1, b0, acc[1][0], 0, 0, 0);
    acc[1][1] = __builtin_amdgcn_mfma_f32_16x16x32_bf16(a1, b1, acc[1][1], 0, 0, 0);
  }
  unsigned short* ob = o + (size_t)bt * 128 * 256 + h * 32;
#pragma unroll
  for (int i = 0; i < 2; ++i)
#pragma unroll
    for (int j = 0; j < 2; ++j)
#pragma unroll
      for (int r = 0; r < 4; ++r) {
        int e = wave * 32 + i * 16 + crow0 + r;
        ob[(size_t)e * 256 + j * 16 + ccol] = f2bf(acc[i][j][r]);
      }
}

// ---------------- residual 1: x1 = x + xs + gamma_s * p2 (f32 out) -----------------
__global__ __launch_bounds__(256) void resid1_kernel(const float* __restrict__ x,
                                                     const unsigned short* __restrict__ xs,
                                                     const unsigned short* __restrict__ p2,
                                                     const float* __restrict__ gs,
                                                     float* __restrict__ x1) {
  size_t i = ((size_t)blockIdx.x * 256 + threadIdx.x) * 4;
  float g = gs[0];
  float4 xv = *(const float4*)(x + i);
  ushort4 s4 = *(const ushort4*)(xs + i);
  ushort4 p4 = *(const ushort4*)(p2 + i);
  float4 r;
  r.x = xv.x + bf2f(s4.x) + g * bf2f(p4.x);
  r.y = xv.y + bf2f(s4.y) + g * bf2f(p4.y);
  r.z = xv.z + bf2f(s4.z) + g * bf2f(p4.z);
  r.w = xv.w + bf2f(s4.w) + g * bf2f(p4.w);
  *(float4*)(x1 + i) = r;
}

// ---------------- prep kernels -----------------------------------------------------
__global__ __launch_bounds__(256) void transcast(const float* __restrict__ src,
                                                 unsigned short* __restrict__ dst,
                                                 int N, int K) {   // dst[n*K+k] = src[k*N+n]
  int idx = blockIdx.x * 256 + threadIdx.x;
  int n = idx / K, k = idx - n * K;
  dst[idx] = f2bf(src[(size_t)k * N + n]);
}
__global__ __launch_bounds__(256) void castbf(const float* __restrict__ s,
                                              unsigned short* __restrict__ d) {
  int i = blockIdx.x * 256 + threadIdx.x;
  d[i] = f2bf(s[i]);
}
__global__ __launch_bounds__(256) void pack_conv1(const float* __restrict__ w1,
                                                  unsigned short* __restrict__ dst) {
  int idx = blockIdx.x * 256 + threadIdx.x;   // 512*768: [h][slab*256+c]
  int hh = idx / 768, kk = idx - hh * 768;
  int slab = kk >> 8, c = kk & 255;
  dst[idx] = f2bf(w1[(size_t)hh * 768 + c * 3 + slab]);
}
__global__ __launch_bounds__(256) void bnfold(const float* __restrict__ w,
                                              const float* __restrict__ bvec,
                                              const float* __restrict__ m,
                                              const float* __restrict__ v,
                                              float* __restrict__ s,
                                              float* __restrict__ o, int n) {
  int i = blockIdx.x * 256 + threadIdx.x;
  if (i < n) {
    float sc = w[i] * rsqrtf(v[i] + EPSF);
    s[i] = sc;
    o[i] = bvec[i] - m[i] * sc;
  }
}
__global__ __launch_bounds__(256) void mask_prep(const int* __restrict__ adj,
                                                 float* __restrict__ maskh) {
  int i = blockIdx.x * 256 + threadIdx.x;   // 16384
  maskh[i] = 0.5f * (float)adj[i];
}
__global__ __launch_bounds__(256) void zero_pad(unsigned short* __restrict__ xt) {
  int idx = blockIdx.x * 256 + threadIdx.x;   // 8 b * 2 rows * 128*256
  int bb = idx >> 16;
  int rem = idx & 65535;
  int which = rem >> 15;      // 0 -> t_pad 0, 1 -> t_pad 65
  int off = rem & 32767;
  size_t base = ((size_t)(bb * 66 + which * 65)) * 128 * 256;
  xt[base + off] = 0;
}

// ---------------- host-side launch --------------------------------------------------
extern "C" void kernel_launch(void* const* d_in, const int* in_sizes, int n_in,
                              void* d_out, int out_size, void* d_ws, size_t ws_size,
                              hipStream_t stream) {
  (void)in_sizes; (void)n_in; (void)out_size; (void)ws_size;
  const float* x       = (const float*)d_in[0];
  const int*   adj     = (const int*)  d_in[1];
  const float* n1_w    = (const float*)d_in[2];
  const float* n1_b    = (const float*)d_in[3];
  const float* q_w     = (const float*)d_in[4];
  const float* k_w     = (const float*)d_in[5];
  const float* v_w     = (const float*)d_in[6];
  const float* proj_w  = (const float*)d_in[7];
  const float* proj_b  = (const float*)d_in[8];
  const float* on_w    = (const float*)d_in[9];
  const float* on_b    = (const float*)d_in[10];
  const float* gamma_s = (const float*)d_in[11];
  const float* conv1_w = (const float*)d_in[12];
  const float* bn1_w   = (const float*)d_in[13];
  const float* bn1_b   = (const float*)d_in[14];
  const float* bn1_m   = (const float*)d_in[15];
  const float* bn1_v   = (const float*)d_in[16];
  const float* conv2_w = (const float*)d_in[17];
  const float* bn2_w   = (const float*)d_in[18];
  const float* bn2_b   = (const float*)d_in[19];
  const float* bn2_m   = (const float*)d_in[20];
  const float* bn2_v   = (const float*)d_in[21];
  const float* tn_w    = (const float*)d_in[22];
  const float* tn_b    = (const float*)d_in[23];
  const float* gamma_t = (const float*)d_in[24];
  const float* n3_w    = (const float*)d_in[25];
  const float* n3_b    = (const float*)d_in[26];
  const float* fc1_w   = (const float*)d_in[27];
  const float* fc1_b   = (const float*)d_in[28];
  const float* fc2_w   = (const float*)d_in[29];
  const float* fc2_b   = (const float*)d_in[30];
  float* O = (float*)d_out;

  const size_t MB = 1024 * 1024;
  char* wsb = (char*)d_ws;
  // live-range overlaid buffers (peak ~170 MB)
  unsigned short* qkvb = (unsigned short*)(wsb + 0);        // 96 MB  [qkv gemm -> attn]
  float*          pjo  = (float*)(wsb + 0);                 // 64 MB  [proj out f32]
  float*          x1b  = (float*)(wsb + 0);                 // 64 MB  [resid1 -> conv2]
  unsigned short* xmb  = (unsigned short*)(wsb + 0);        // 32 MB  [ln3 -> fc1]
  unsigned short* hb   = (unsigned short*)(wsb + 32 * MB);  // 128 MB [fc1 -> fc2]
  unsigned short* xtp  = (unsigned short*)(wsb + 64 * MB);  // 33 MB  [ln_t -> conv1]
  unsigned short* xsb  = (unsigned short*)(wsb + 96 * MB);  // 32 MB  [ln1 -> resid1]
  unsigned short* oat  = (unsigned short*)(wsb + 128 * MB); // 32 MB  [attn -> proj]
  unsigned short* p2b  = (unsigned short*)(wsb + 128 * MB); // 32 MB  [ln_o -> resid1]
  unsigned short* y1b  = (unsigned short*)(wsb + 100 * MB); // 64 MB  [conv1 -> conv2]
  char* wp = wsb + 164 * MB;
  unsigned short* Wqkv = (unsigned short*)wp;  wp += 768 * 256 * 2;
  unsigned short* PjT  = (unsigned short*)wp;  wp += 256 * 256 * 2;
  unsigned short* W1t  = (unsigned short*)wp;  wp += 512 * 768 * 2;
  unsigned short* W2t  = (unsigned short*)wp;  wp += 256 * 512 * 2;
  unsigned short* F1t  = (unsigned short*)wp;  wp += 1024 * 256 * 2;
  unsigned short* F2t  = (unsigned short*)wp;  wp += 256 * 1024 * 2;
  float* s1 = (float*)wp; wp += 512 * 4;
  float* o1 = (float*)wp; wp += 512 * 4;
  float* s2 = (float*)wp; wp += 256 * 4;
  float* o2 = (float*)wp; wp += 256 * 4;
  float* maskh = (float*)wp; wp += 16384 * 4;

  // ---- prep (cheap, once per launch) ----
  transcast<<<768 * 256 / 256, 256, 0, stream>>>(q_w, Wqkv, 256, 256);
  transcast<<<768 * 256 / 256, 256, 0, stream>>>(k_w, Wqkv + 256 * 256, 256, 256);
  transcast<<<768 * 256 / 256, 256, 0, stream>>>(v_w, Wqkv + 512 * 256, 256, 256);
  transcast<<<256 * 256 / 256, 256, 0, stream>>>(proj_w, PjT, 256, 256);
  pack_conv1<<<512 * 768 / 256, 256, 0, stream>>>(conv1_w, W1t);
  castbf<<<256 * 512 / 256, 256, 0, stream>>>(conv2_w, W2t);   // already [C][H] = [N][K]
  transcast<<<1024 * 256 / 256, 256, 0, stream>>>(fc1_w, F1t, 1024, 256);
  transcast<<<256 * 1024 / 256, 256, 0, stream>>>(fc2_w, F2t, 256, 1024);
  bnfold<<<2, 256, 0, stream>>>(bn1_w, bn1_b, bn1_m, bn1_v, s1, o1, 512);
  bnfold<<<1, 256, 0, stream>>>(bn2_w, bn2_b, bn2_m, bn2_v, s2, o2, 256);
  mask_prep<<<64, 256, 0, stream>>>(adj, maskh);
  zero_pad<<<524288 / 256, 256, 0, stream>>>(xtp);

  // ---- spatial attention branch ----
  ln256_bf<false><<<NTOK / 4, 256, 0, stream>>>(x, n1_w, n1_b, xsb);
  mfma_gemm<0, false><<<dim3(6, 512), 256, 0, stream>>>(xsb, Wqkv, nullptr, nullptr, nullptr, nullptr, qkvb, 256, 768);
  attn_mfma<<<Bn * Tn * NHd, 256, 0, stream>>>(qkvb, maskh, oat);
  mfma_gemm<5, false><<<dim3(2, 512), 256, 0, stream>>>(oat, PjT, nullptr, proj_b, nullptr, nullptr, pjo, 256, 256);
  ln256_bf<false><<<NTOK / 4, 256, 0, stream>>>(pjo, on_w, on_b, p2b);
  resid1_kernel<<<(int)(SZ / (4 * 256)), 256, 0, stream>>>(x, xsb, p2b, gamma_s, x1b);

  // ---- temporal conv branch ----
  ln256_bf<true><<<NTOK / 4, 256, 0, stream>>>(x1b, tn_w, tn_b, xtp);
  mfma_gemm<2, true><<<dim3(4, 512), 256, 0, stream>>>(xtp, W1t, s1, o1, nullptr, nullptr, y1b, 768, 512);
  mfma_gemm<3, false><<<dim3(2, 512), 256, 0, stream>>>(y1b, W2t, s2, o2, x1b, gamma_t, O, 512, 256);

  // ---- MLP ----
  ln256_bf<false><<<NTOK / 4, 256, 0, stream>>>(O, n3_w, n3_b, xmb);
  mfma_gemm<2, false><<<dim3(8, 512), 256, 0, stream>>>(xmb, F1t, nullptr, fc1_b, nullptr, nullptr, hb, 256, 1024);
  mfma_gemm<4, false><<<dim3(2, 512), 256, 0, stream>>>(hb, F2t, nullptr, fc2_b, O, nullptr, O, 1024, 256);
}

// Round 2
// 607.518 us; speedup vs baseline: 1.2219x; 1.1421x over previous
//
#include <hip/hip_runtime.h>
#include <cstdint>

// ---- problem constants ----
constexpr int Bn = 8, Tn = 64, En = 128, Cn = 256;
constexpr int Hn = 512, Mn = 1024, NHd = 8, Dn = 32;
constexpr int NTOK = Bn * Tn * En;          // 65536 tokens
constexpr size_t SZ = (size_t)NTOK * Cn;    // 16,777,216 elements
#define EPSF 1e-5f

typedef __attribute__((ext_vector_type(8))) short short8;
typedef __attribute__((ext_vector_type(4))) float f32x4;

__device__ __forceinline__ float bf2f(unsigned short u) {
  union { unsigned int i; float f; } c; c.i = ((unsigned int)u) << 16; return c.f;
}
__device__ __forceinline__ unsigned short f2bf(float f) {
  union { float f; unsigned int i; } c; c.f = f;
  unsigned int u = c.i;
  return (unsigned short)((u + 0x7fffu + ((u >> 16) & 1u)) >> 16);
}
// tanh-approx GELU (x * sigmoid(1.5957691*(x+0.044715x^3))), ~7 VALU ops vs ~25
// for erff. Max abs error ~1e-3, far below bf16 rounding already in the pipe.
__device__ __forceinline__ float gelu_f(float v) {
  float x2 = v * v;
  float p = v * fmaf(x2, 0.10294532f, 2.30221000f);   // 2u*log2(e)
  float d = 1.0f + __builtin_amdgcn_exp2f(-p);
  return v * __builtin_amdgcn_rcpf(d);
}

// async global->LDS, 16B per lane; lds dest = wave-uniform base + lane*16
__device__ __forceinline__ void gload16(const unsigned short* g, unsigned short* l) {
  __builtin_amdgcn_global_load_lds(
      (const __attribute__((address_space(1))) unsigned int*)g,
      (__attribute__((address_space(3))) unsigned int*)l, 16, 0, 0);
}

#define MEMFENCE() asm volatile("" ::: "memory")

// ---------------- MFMA GEMM: out[M,N] = A[M,K](bf16) @ Bt[N,K]^T (bf16) ------------
// v3: 256x256 tile, BK=32, 512 threads (8 waves, 2Mx4N), 4-slot LDS rotation
// (128 KiB). Tile T+3 is staged (global_load_lds) during tile T, so a slot is
// overwritten only 3 tiles after its last read; one s_barrier per K-tile
// guarantees all waves passed those reads. Counted s_waitcnt vmcnt(8) (never 0
// in the main loop) keeps 2 tiles in flight => ~3 tile-times (~1000cy) of
// latency cover. Two 16-MFMA phases per tile with s_setprio around MFMA.
// BK=32 rows are 64B so b128 fragment reads are bank-conflict-free (8 lanes
// per bank-quad = minimum), no swizzle needed.
// EPI: 0 = bf16 plain; 1 = bf16 +bias; 2 = bf16 gelu(acc*scale+bias);
//      3 = f32 2*res + g*(acc*scale+bias); 4 = f32 res + acc + bias;
//      5 = f32 acc + bias.
// C1A: conv1 A-addressing over t-padded buffer [b][66][e][c], slab = k0>>8.
template <int EPI, bool C1A>
__global__ __launch_bounds__(512) void mfma_gemm(
    const unsigned short* __restrict__ A,
    const unsigned short* __restrict__ Bt,
    const float* __restrict__ scale,
    const float* __restrict__ bias,
    const float* __restrict__ resf,
    const float* __restrict__ gscal,
    void* __restrict__ outv,
    int K, int N) {
  __shared__ unsigned short lds[4][2][8192];   // [slot][A|B][256*32]
  int tid = threadIdx.x;
  int lane = tid & 63, wave = tid >> 6;
  int wr = wave >> 2, wc = wave & 3;           // wave grid 2(M) x 4(N)

  // XCD-aware chunked swizzle (all grids here have nwg % 8 == 0)
  int nwg = gridDim.x * gridDim.y;
  int flat = blockIdx.y * gridDim.x + blockIdx.x;
  int cpx = nwg >> 3;
  int swz = (flat & 7) * cpx + (flat >> 3);
  int ntile = swz % gridDim.x;
  int mtile = swz / gridDim.x;
  int rowBase = mtile * 256;
  int colBase = ntile * 256;
  int lda = C1A ? 256 : K;

  // fragment LDS offsets (ushort units); 64B rows -> conflict-free b128 reads
  int arow = lane & 15, g8 = (lane >> 4) * 8;
  int aoff[8], boff[4];
#pragma unroll
  for (int m = 0; m < 8; ++m) aoff[m] = (wr * 128 + m * 16 + arow) * 32 + g8;
#pragma unroll
  for (int n = 0; n < 4; ++n) boff[n] = (wc * 64 + n * 16 + arow) * 32 + g8;

  f32x4 acc[8][4];
#pragma unroll
  for (int m = 0; m < 8; ++m)
#pragma unroll
    for (int n = 0; n < 4; ++n) acc[m][n] = (f32x4)(0.0f);

  int srow = lane >> 2;          // row within 16-row stage chunk
  int scol = (lane & 3) * 8;     // halfword col within 32-col row

  // stage one 256x32 A-unit (16KB = 512thr x 16B x 2) for tile T
  auto stageA = [&](int T) {
    int k0 = T << 5, slot = T & 3;
#pragma unroll
    for (int r = 0; r < 2; ++r) {
      int row = r * 128 + wave * 16 + srow;
      const unsigned short* src;
      if (C1A) {
        int idx = rowBase + row;
        int bb = idx >> 13, tt = (idx >> 7) & 63, e = idx & 127;
        src = A + ((size_t)((bb * 66 + tt + (k0 >> 8)) * 128 + e)) * 256 +
              (k0 & 255) + scol;
      } else {
        src = A + (size_t)(rowBase + row) * lda + k0 + scol;
      }
      gload16(src, &lds[slot][0][r * 4096 + wave * 512]);
    }
  };
  auto stageB = [&](int T) {
    int k0 = T << 5, slot = T & 3;
#pragma unroll
    for (int r = 0; r < 2; ++r) {
      int row = r * 128 + wave * 16 + srow;
      const unsigned short* src = Bt + (size_t)(colBase + row) * K + k0 + scol;
      gload16(src, &lds[slot][1][r * 4096 + wave * 512]);
    }
  };

  // one K-tile: vmcnt gate -> barrier -> stage(T+3) -> 2 phases of 16 MFMA
  auto tile = [&](int T, int vm, bool st) {
    if (vm == 8)      asm volatile("s_waitcnt vmcnt(8)" ::: "memory");
    else if (vm == 4) asm volatile("s_waitcnt vmcnt(4)" ::: "memory");
    else              asm volatile("s_waitcnt vmcnt(0)" ::: "memory");
    __builtin_amdgcn_sched_barrier(0);
    __builtin_amdgcn_s_barrier();
    MEMFENCE();
    if (st) stageA(T + 3);                     // writes slot (T-1)&3: safe, all
                                               // waves passed its last read
    const unsigned short* as = &lds[T & 3][0][0];
    const unsigned short* bs = &lds[T & 3][1][0];
    short8 bfr[4], af[4];
#pragma unroll
    for (int n = 0; n < 4; ++n) bfr[n] = *(const short8*)(bs + boff[n]);
#pragma unroll
    for (int m = 0; m < 4; ++m) af[m] = *(const short8*)(as + aoff[m]);
    __builtin_amdgcn_s_setprio(1);
#pragma unroll
    for (int m = 0; m < 4; ++m)
#pragma unroll
      for (int n = 0; n < 4; ++n)
        acc[m][n] = __builtin_amdgcn_mfma_f32_16x16x32_bf16(af[m], bfr[n], acc[m][n], 0, 0, 0);
    __builtin_amdgcn_s_setprio(0);
    if (st) stageB(T + 3);
#pragma unroll
    for (int m = 0; m < 4; ++m) af[m] = *(const short8*)(as + aoff[4 + m]);
    __builtin_amdgcn_s_setprio(1);
#pragma unroll
    for (int m = 0; m < 4; ++m)
#pragma unroll
      for (int n = 0; n < 4; ++n)
        acc[4 + m][n] = __builtin_amdgcn_mfma_f32_16x16x32_bf16(af[m], bfr[n], acc[4 + m][n], 0, 0, 0);
    __builtin_amdgcn_s_setprio(0);
  };

  // prologue: tiles 0..2 staged (12 loads in flight)
  stageA(0); stageB(0); stageA(1); stageB(1); stageA(2); stageB(2);
  int nkt = K >> 5;                            // >= 8 for all call sites
  for (int T = 0; T < nkt - 3; ++T) tile(T, 8, true);
  tile(nkt - 3, 8, false);
  tile(nkt - 2, 4, false);
  tile(nkt - 1, 0, false);
  MEMFENCE();   // keep epilogue loads below the counted-vmcnt region

  int crow0 = (lane >> 4) * 4, ccol = lane & 15;
  size_t rb = (size_t)rowBase + wr * 128;
  int cb = colBase + wc * 64;
  float gt = (EPI == 3) ? gscal[0] : 0.f;
  float bi[4], sc[4];
#pragma unroll
  for (int n = 0; n < 4; ++n) {
    int col = cb + n * 16 + ccol;
    bi[n] = (EPI >= 1 && bias) ? bias[col] : 0.f;
    sc[n] = ((EPI == 2 || EPI == 3) && scale) ? scale[col] : 1.f;
  }
#pragma unroll
  for (int m = 0; m < 8; ++m) {
#pragma unroll
    for (int n = 0; n < 4; ++n) {
      int col = cb + n * 16 + ccol;
#pragma unroll
      for (int r = 0; r < 4; ++r) {
        size_t row = rb + m * 16 + crow0 + r;
        size_t idx = row * (size_t)N + col;
        float v = acc[m][n][r];
        if (EPI == 0)      ((unsigned short*)outv)[idx] = f2bf(v);
        else if (EPI == 1) ((unsigned short*)outv)[idx] = f2bf(v + bi[n]);
        else if (EPI == 2) ((unsigned short*)outv)[idx] = f2bf(gelu_f(v * sc[n] + bi[n]));
        else if (EPI == 3) ((float*)outv)[idx] = 2.0f * resf[idx] + gt * (v * sc[n] + bi[n]);
        else if (EPI == 4) ((float*)outv)[idx] = resf[idx] + v + bi[n];
        else if (EPI == 5) ((float*)outv)[idx] = v + bi[n];
      }
    }
  }
}

// ---------------- LayerNorm f32 -> bf16, one wave per token ------------------------
template <bool PAD>
__global__ __launch_bounds__(256) void ln256_bf(const float* __restrict__ src,
                                                const float* __restrict__ w,
                                                const float* __restrict__ b,
                                                unsigned short* __restrict__ dst) {
  int lane = threadIdx.x & 63;
  int tok = blockIdx.x * 4 + (threadIdx.x >> 6);
  const float4* row = (const float4*)(src + (size_t)tok * Cn);
  float4 v = row[lane];
  float s  = v.x + v.y + v.z + v.w;
  float s2 = v.x*v.x + v.y*v.y + v.z*v.z + v.w*v.w;
#pragma unroll
  for (int off = 32; off >= 1; off >>= 1) {
    s  += __shfl_xor(s, off, 64);
    s2 += __shfl_xor(s2, off, 64);
  }
  float mean = s * (1.0f / Cn);
  float var = fmaxf(s2 * (1.0f / Cn) - mean * mean, 0.0f);
  float r = rsqrtf(var + EPSF);
  float4 wv = ((const float4*)w)[lane];
  float4 bv = ((const float4*)b)[lane];
  size_t dtok = tok;
  if (PAD) {
    int bb = tok >> 13, tt = (tok >> 7) & 63, e = tok & 127;
    dtok = ((size_t)(bb * 66 + tt + 1)) * 128 + e;
  }
  ushort4 o;
  o.x = f2bf((v.x - mean) * r * wv.x + bv.x);
  o.y = f2bf((v.y - mean) * r * wv.y + bv.y);
  o.z = f2bf((v.z - mean) * r * wv.z + bv.z);
  o.w = f2bf((v.w - mean) * r * wv.w + bv.w);
  *(ushort4*)(dst + dtok * Cn + lane * 4) = o;
}

// ---------------- MFMA spatial attention, one block per (frame, head) --------------
// qkv: [bt*128+e][768]  (q|k|v each 256 wide, head h at h*32)
// maskh: 0.5 * adj  [128*128] f32.   P = maskh*S + 0.5  (== (S*m+1)*0.5)
__global__ __launch_bounds__(256) void attn_mfma(const unsigned short* __restrict__ qkv,
                                                 const float* __restrict__ maskh,
                                                 unsigned short* __restrict__ o) {
  __shared__ unsigned short Qs[128 * 32];
  __shared__ unsigned short Ks[128 * 32];
  __shared__ unsigned short Vt[32 * 136];    // [d][f], padded
  __shared__ unsigned short Ps[128 * 136];   // [e][f], padded
  int tid = threadIdx.x, lane = tid & 63, wave = tid >> 6;
  int h = blockIdx.x & 7, bt = blockIdx.x >> 3;
  size_t gbase = (size_t)bt * 128 * 768 + h * 32;
  // stage Q,K via global_load_lds (each wave: 2 chunks of 16 rows = 1 KB each)
#pragma unroll
  for (int i = 0; i < 2; ++i) {
    int q = wave * 2 + i;
    int row = q * 16 + (lane >> 2);
    int seg = (lane & 3) * 8;
    gload16(qkv + gbase + (size_t)row * 768 + seg, &Qs[q * 512]);
    gload16(qkv + gbase + 256 + (size_t)row * 768 + seg, &Ks[q * 512]);
  }
  // stage V transposed (scalar writes, ~2-way conflicts)
  {
    int e = tid >> 1, dh = (tid & 1) * 16;
    const unsigned short* gv = qkv + gbase + 512 + (size_t)e * 768 + dh;
    short8 v0 = *(const short8*)gv;
    short8 v1 = *(const short8*)(gv + 8);
#pragma unroll
    for (int j = 0; j < 8; ++j) {
      Vt[(dh + j) * 136 + e]     = (unsigned short)v0[j];
      Vt[(dh + 8 + j) * 136 + e] = (unsigned short)v1[j];
    }
  }
  __syncthreads();
  // ---- S = Q K^T for rows [32*wave, 32*wave+32), apply mask, write P to LDS ----
  int arow = lane & 15, akk = (lane >> 4) * 8;
  int crow0 = (lane >> 4) * 4, ccol = lane & 15;
  short8 af0 = *(const short8*)&Qs[(wave * 32 + arow) * 32 + akk];
  short8 af1 = *(const short8*)&Qs[(wave * 32 + 16 + arow) * 32 + akk];
#pragma unroll
  for (int j = 0; j < 8; ++j) {
    short8 bfr = *(const short8*)&Ks[(j * 16 + arow) * 32 + akk];
    f32x4 s0 = __builtin_amdgcn_mfma_f32_16x16x32_bf16(af0, bfr, (f32x4)(0.0f), 0, 0, 0);
    f32x4 s1 = __builtin_amdgcn_mfma_f32_16x16x32_bf16(af1, bfr, (f32x4)(0.0f), 0, 0, 0);
    int f = j * 16 + ccol;
#pragma unroll
    for (int r = 0; r < 4; ++r) {
      int e0 = wave * 32 + crow0 + r;
      int e1 = e0 + 16;
      Ps[e0 * 136 + f] = f2bf(maskh[e0 * 128 + f] * s0[r] + 0.5f);
      Ps[e1 * 136 + f] = f2bf(maskh[e1 * 128 + f] * s1[r] + 0.5f);
    }
  }
  // ---- O = P V for the same rows (wave reads only rows it wrote: no barrier) ----
  f32x4 acc[2][2];
#pragma unroll
  for (int i = 0; i < 2; ++i)
#pragma unroll
    for (int j = 0; j < 2; ++j) acc[i][j] = (f32x4)(0.0f);
#pragma unroll
  for (int k0 = 0; k0 < 128; k0 += 32) {
    short8 a0 = *(const short8*)&Ps[(wave * 32 + arow) * 136 + k0 + akk];
    short8 a1 = *(const short8*)&Ps[(wave * 32 + 16 + arow) * 136 + k0 + akk];
    short8 b0 = *(const short8*)&Vt[arow * 136 + k0 + akk];
    short8 b1 = *(const short8*)&Vt[(16 + arow) * 136 + k0 + akk];
    acc[0][0] = __builtin_amdgcn_mfma_f32_16x16x32_bf16(a0, b0, acc[0][0], 0, 0, 0);
    acc[0][1] = __builtin_amdgcn_mfma_f32_16x16x32_bf16(a0, b1, acc[0][1], 0, 0, 0);
    acc[1][0] = __builtin_amdgcn_mfma_f32_16x16x32_bf16(a1, b0, acc[1][0], 0, 0, 0);
    acc[1][1] = __builtin_amdgcn_mfma_f32_16x16x32_bf16(a1, b1, acc[1][1], 0, 0, 0);
  }
  unsigned short* ob = o + (size_t)bt * 128 * 256 + h * 32;
#pragma unroll
  for (int i = 0; i < 2; ++i)
#pragma unroll
    for (int j = 0; j < 2; ++j)
#pragma unroll
      for (int r = 0; r < 4; ++r) {
        int e = wave * 32 + i * 16 + crow0 + r;
        ob[(size_t)e * 256 + j * 16 + ccol] = f2bf(acc[i][j][r]);
      }
}

// ---------------- residual 1: x1 = x + xs + gamma_s * p2 (f32 out) -----------------
__global__ __launch_bounds__(256) void resid1_kernel(const float* __restrict__ x,
                                                     const unsigned short* __restrict__ xs,
                                                     const unsigned short* __restrict__ p2,
                                                     const float* __restrict__ gs,
                                                     float* __restrict__ x1) {
  size_t i = ((size_t)blockIdx.x * 256 + threadIdx.x) * 4;
  float g = gs[0];
  float4 xv = *(const float4*)(x + i);
  ushort4 s4 = *(const ushort4*)(xs + i);
  ushort4 p4 = *(const ushort4*)(p2 + i);
  float4 r;
  r.x = xv.x + bf2f(s4.x) + g * bf2f(p4.x);
  r.y = xv.y + bf2f(s4.y) + g * bf2f(p4.y);
  r.z = xv.z + bf2f(s4.z) + g * bf2f(p4.z);
  r.w = xv.w + bf2f(s4.w) + g * bf2f(p4.w);
  *(float4*)(x1 + i) = r;
}

// ---------------- prep kernels -----------------------------------------------------
__global__ __launch_bounds__(256) void transcast(const float* __restrict__ src,
                                                 unsigned short* __restrict__ dst,
                                                 int N, int K) {   // dst[n*K+k] = src[k*N+n]
  int idx = blockIdx.x * 256 + threadIdx.x;
  int n = idx / K, k = idx - n * K;
  dst[idx] = f2bf(src[(size_t)k * N + n]);
}
__global__ __launch_bounds__(256) void castbf(const float* __restrict__ s,
                                              unsigned short* __restrict__ d) {
  int i = blockIdx.x * 256 + threadIdx.x;
  d[i] = f2bf(s[i]);
}
__global__ __launch_bounds__(256) void pack_conv1(const float* __restrict__ w1,
                                                  unsigned short* __restrict__ dst) {
  int idx = blockIdx.x * 256 + threadIdx.x;   // 512*768: [h][slab*256+c]
  int hh = idx / 768, kk = idx - hh * 768;
  int slab = kk >> 8, c = kk & 255;
  dst[idx] = f2bf(w1[(size_t)hh * 768 + c * 3 + slab]);
}
__global__ __launch_bounds__(256) void bnfold(const float* __restrict__ w,
                                              const float* __restrict__ bvec,
                                              const float* __restrict__ m,
                                              const float* __restrict__ v,
                                              float* __restrict__ s,
                                              float* __restrict__ o, int n) {
  int i = blockIdx.x * 256 + threadIdx.x;
  if (i < n) {
    float sc = w[i] * rsqrtf(v[i] + EPSF);
    s[i] = sc;
    o[i] = bvec[i] - m[i] * sc;
  }
}
__global__ __launch_bounds__(256) void mask_prep(const int* __restrict__ adj,
                                                 float* __restrict__ maskh) {
  int i = blockIdx.x * 256 + threadIdx.x;   // 16384
  maskh[i] = 0.5f * (float)adj[i];
}
__global__ __launch_bounds__(256) void zero_pad(unsigned short* __restrict__ xt) {
  int idx = blockIdx.x * 256 + threadIdx.x;   // 8 b * 2 rows * 128*256
  int bb = idx >> 16;
  int rem = idx & 65535;
  int which = rem >> 15;      // 0 -> t_pad 0, 1 -> t_pad 65
  int off = rem & 32767;
  size_t base = ((size_t)(bb * 66 + which * 65)) * 128 * 256;
  xt[base + off] = 0;
}

// ---------------- host-side launch --------------------------------------------------
extern "C" void kernel_launch(void* const* d_in, const int* in_sizes, int n_in,
                              void* d_out, int out_size, void* d_ws, size_t ws_size,
                              hipStream_t stream) {
  (void)in_sizes; (void)n_in; (void)out_size; (void)ws_size;
  const float* x       = (const float*)d_in[0];
  const int*   adj     = (const int*)  d_in[1];
  const float* n1_w    = (const float*)d_in[2];
  const float* n1_b    = (const float*)d_in[3];
  const float* q_w     = (const float*)d_in[4];
  const float* k_w     = (const float*)d_in[5];
  const float* v_w     = (const float*)d_in[6];
  const float* proj_w  = (const float*)d_in[7];
  const float* proj_b  = (const float*)d_in[8];
  const float* on_w    = (const float*)d_in[9];
  const float* on_b    = (const float*)d_in[10];
  const float* gamma_s = (const float*)d_in[11];
  const float* conv1_w = (const float*)d_in[12];
  const float* bn1_w   = (const float*)d_in[13];
  const float* bn1_b   = (const float*)d_in[14];
  const float* bn1_m   = (const float*)d_in[15];
  const float* bn1_v   = (const float*)d_in[16];
  const float* conv2_w = (const float*)d_in[17];
  const float* bn2_w   = (const float*)d_in[18];
  const float* bn2_b   = (const float*)d_in[19];
  const float* bn2_m   = (const float*)d_in[20];
  const float* bn2_v   = (const float*)d_in[21];
  const float* tn_w    = (const float*)d_in[22];
  const float* tn_b    = (const float*)d_in[23];
  const float* gamma_t = (const float*)d_in[24];
  const float* n3_w    = (const float*)d_in[25];
  const float* n3_b    = (const float*)d_in[26];
  const float* fc1_w   = (const float*)d_in[27];
  const float* fc1_b   = (const float*)d_in[28];
  const float* fc2_w   = (const float*)d_in[29];
  const float* fc2_b   = (const float*)d_in[30];
  float* O = (float*)d_out;

  const size_t MB = 1024 * 1024;
  char* wsb = (char*)d_ws;
  // live-range overlaid buffers (peak ~170 MB)
  unsigned short* qkvb = (unsigned short*)(wsb + 0);        // 96 MB  [qkv gemm -> attn]
  float*          pjo  = (float*)(wsb + 0);                 // 64 MB  [proj out f32]
  float*          x1b  = (float*)(wsb + 0);                 // 64 MB  [resid1 -> conv2]
  unsigned short* xmb  = (unsigned short*)(wsb + 0);        // 32 MB  [ln3 -> fc1]
  unsigned short* hb   = (unsigned short*)(wsb + 32 * MB);  // 128 MB [fc1 -> fc2]
  unsigned short* xtp  = (unsigned short*)(wsb + 64 * MB);  // 33 MB  [ln_t -> conv1]
  unsigned short* xsb  = (unsigned short*)(wsb + 96 * MB);  // 32 MB  [ln1 -> resid1]
  unsigned short* oat  = (unsigned short*)(wsb + 128 * MB); // 32 MB  [attn -> proj]
  unsigned short* p2b  = (unsigned short*)(wsb + 128 * MB); // 32 MB  [ln_o -> resid1]
  unsigned short* y1b  = (unsigned short*)(wsb + 100 * MB); // 64 MB  [conv1 -> conv2]
  char* wp = wsb + 164 * MB;
  unsigned short* Wqkv = (unsigned short*)wp;  wp += 768 * 256 * 2;
  unsigned short* PjT  = (unsigned short*)wp;  wp += 256 * 256 * 2;
  unsigned short* W1t  = (unsigned short*)wp;  wp += 512 * 768 * 2;
  unsigned short* W2t  = (unsigned short*)wp;  wp += 256 * 512 * 2;
  unsigned short* F1t  = (unsigned short*)wp;  wp += 1024 * 256 * 2;
  unsigned short* F2t  = (unsigned short*)wp;  wp += 256 * 1024 * 2;
  float* s1 = (float*)wp; wp += 512 * 4;
  float* o1 = (float*)wp; wp += 512 * 4;
  float* s2 = (float*)wp; wp += 256 * 4;
  float* o2 = (float*)wp; wp += 256 * 4;
  float* maskh = (float*)wp; wp += 16384 * 4;

  // ---- prep (cheap, once per launch) ----
  transcast<<<768 * 256 / 256, 256, 0, stream>>>(q_w, Wqkv, 256, 256);
  transcast<<<768 * 256 / 256, 256, 0, stream>>>(k_w, Wqkv + 256 * 256, 256, 256);
  transcast<<<768 * 256 / 256, 256, 0, stream>>>(v_w, Wqkv + 512 * 256, 256, 256);
  transcast<<<256 * 256 / 256, 256, 0, stream>>>(proj_w, PjT, 256, 256);
  pack_conv1<<<512 * 768 / 256, 256, 0, stream>>>(conv1_w, W1t);
  castbf<<<256 * 512 / 256, 256, 0, stream>>>(conv2_w, W2t);   // already [C][H] = [N][K]
  transcast<<<1024 * 256 / 256, 256, 0, stream>>>(fc1_w, F1t, 1024, 256);
  transcast<<<256 * 1024 / 256, 256, 0, stream>>>(fc2_w, F2t, 256, 1024);
  bnfold<<<2, 256, 0, stream>>>(bn1_w, bn1_b, bn1_m, bn1_v, s1, o1, 512);
  bnfold<<<1, 256, 0, stream>>>(bn2_w, bn2_b, bn2_m, bn2_v, s2, o2, 256);
  mask_prep<<<64, 256, 0, stream>>>(adj, maskh);
  zero_pad<<<524288 / 256, 256, 0, stream>>>(xtp);

  // ---- spatial attention branch ----
  ln256_bf<false><<<NTOK / 4, 256, 0, stream>>>(x, n1_w, n1_b, xsb);
  mfma_gemm<0, false><<<dim3(3, 256), 512, 0, stream>>>(xsb, Wqkv, nullptr, nullptr, nullptr, nullptr, qkvb, 256, 768);
  attn_mfma<<<Bn * Tn * NHd, 256, 0, stream>>>(qkvb, maskh, oat);
  mfma_gemm<5, false><<<dim3(1, 256), 512, 0, stream>>>(oat, PjT, nullptr, proj_b, nullptr, nullptr, pjo, 256, 256);
  ln256_bf<false><<<NTOK / 4, 256, 0, stream>>>(pjo, on_w, on_b, p2b);
  resid1_kernel<<<(int)(SZ / (4 * 256)), 256, 0, stream>>>(x, xsb, p2b, gamma_s, x1b);

  // ---- temporal conv branch ----
  ln256_bf<true><<<NTOK / 4, 256, 0, stream>>>(x1b, tn_w, tn_b, xtp);
  mfma_gemm<2, true><<<dim3(2, 256), 512, 0, stream>>>(xtp, W1t, s1, o1, nullptr, nullptr, y1b, 768, 512);
  mfma_gemm<3, false><<<dim3(1, 256), 512, 0, stream>>>(y1b, W2t, s2, o2, x1b, gamma_t, O, 512, 256);

  // ---- MLP ----
  ln256_bf<false><<<NTOK / 4, 256, 0, stream>>>(O, n3_w, n3_b, xmb);
  mfma_gemm<2, false><<<dim3(4, 256), 512, 0, stream>>>(xmb, F1t, nullptr, fc1_b, nullptr, nullptr, hb, 256, 1024);
  mfma_gemm<4, false><<<dim3(1, 256), 512, 0, stream>>>(hb, F2t, nullptr, fc2_b, O, nullptr, O, 1024, 256);
}